// Round 10
// baseline (130.604 us; speedup 1.0000x reference)
//
#include <hip/hip_runtime.h>
#include <math.h>

#define NS 512
#define NU 32
#define ND 512
#define GEPS 1e-6f

typedef float f4 __attribute__((ext_vector_type(4)));
typedef _Float16 half8 __attribute__((ext_vector_type(8)));

// ws layout: bpk[32*16*1024] f16 (1 MiB) | cn2[NS] | dn2[NS*NU] | apk[NS*2*16*1024] f16 (33.5 MiB)
// bpk chunk (ct_g, t): 1024 halves [hi 512 | lo 512], elem l*8+j = cent[col=ct_g*16+(l&15)][k=t*32+(l>>4)*8+j]
// apk chunk (s, rt, t): 1024 halves [hi 512 | lo 512], elem l*8+j = dvec[s][row=rt*16+(l&15)][k=t*32+(l>>4)*8+j]

// prep v4: phase A = chunk-native apk pack + register dn2 (2 shfls/thread total);
// phase B = R4-verified centroid column loop (L2-hot re-read) + bpk scatter.
__global__ __launch_bounds__(256) void prep_full(const float* __restrict__ dvecs,
                                                 _Float16* __restrict__ bpk,
                                                 float* __restrict__ cn2,
                                                 float* __restrict__ dn2,
                                                 _Float16* __restrict__ apk) {
    const int s = blockIdx.x, t = threadIdx.x;
    const int l = t & 63, w = t >> 6, l15 = l & 15, lg = l >> 4;
    const int rt = w >> 1, tkh = (w & 1) * 8;
    const float* base = dvecs + (size_t)s * NU * ND;
    __shared__ float dn2p[4][16];
    __shared__ float red[4];

    // ---- phase A: apk pack + dn2 ----
    const int u = rt * 16 + l15;
    const float* rowp = base + (size_t)u * ND;
    float q = 0.f;
    #pragma unroll
    for (int i = 0; i < 8; ++i) {
        const int tk = tkh + i;
        const int k0 = tk * 32 + lg * 8;
        f4 a0 = *(const f4*)(rowp + k0);
        f4 a1 = *(const f4*)(rowp + k0 + 4);
        q += a0[0]*a0[0] + a0[1]*a0[1] + a0[2]*a0[2] + a0[3]*a0[3]
           + a1[0]*a1[0] + a1[1]*a1[1] + a1[2]*a1[2] + a1[3]*a1[3];
        half8 h, lo;
        #pragma unroll
        for (int c = 0; c < 4; ++c) {
            _Float16 h0 = (_Float16)a0[c];
            h[c]     = h0; lo[c]     = (_Float16)(a0[c] - (float)h0);
            _Float16 h1 = (_Float16)a1[c];
            h[4 + c] = h1; lo[4 + c] = (_Float16)(a1[c] - (float)h1);
        }
        _Float16* cb = apk + ((size_t)(s * 2 + rt) * 16 + tk) * 1024 + l * 8;
        *(half8*)cb         = h;
        *(half8*)(cb + 512) = lo;
    }
    q += __shfl_xor(q, 16);
    q += __shfl_xor(q, 32);
    if (lg == 0) dn2p[w][l15] = q;

    // ---- phase B: centroid (verified R4 pattern; rows L2-hot after phase A) ----
    const int d0 = t * 2;
    float sx = 0.f, sy = 0.f;
    #pragma unroll 4
    for (int u2 = 0; u2 < NU; ++u2) {
        float2 v = *(const float2*)(base + u2 * ND + d0);
        sx += v.x; sy += v.y;
    }
    sx *= (1.0f / NU); sy *= (1.0f / NU);
    float c2 = sx * sx + sy * sy;
    #pragma unroll
    for (int m = 1; m < 64; m <<= 1) c2 += __shfl_xor(c2, m);
    if ((t & 63) == 0) red[t >> 6] = c2;
    __syncthreads();
    if (t < 32)
        dn2[s * NU + t] = dn2p[(t >> 4) * 2][t & 15] + dn2p[(t >> 4) * 2 + 1][t & 15];
    if (t == 0) cn2[s] = red[0] + red[1] + red[2] + red[3];

    // bpk scatter (byte-identical to verified layout)
    _Float16 hx = (_Float16)sx, hy = (_Float16)sy;
    _Float16 lx = (_Float16)(sx - (float)hx), ly = (_Float16)(sy - (float)hy);
    const int ct_g = s >> 4, cl15 = s & 15;
    const int tt = d0 >> 5, blg = (d0 >> 3) & 3, j = d0 & 7;   // j even
    size_t hbase = ((size_t)(ct_g * 16 + tt)) * 1024 + (blg * 16 + cl15) * 8 + j;
    unsigned hi2 = (unsigned)__builtin_bit_cast(unsigned short, hx)
                 | ((unsigned)__builtin_bit_cast(unsigned short, hy) << 16);
    unsigned lo2 = (unsigned)__builtin_bit_cast(unsigned short, lx)
                 | ((unsigned)__builtin_bit_cast(unsigned short, ly) << 16);
    *(unsigned*)(bpk + hbase)       = hi2;
    *(unsigned*)(bpk + hbase + 512) = lo2;
}

// ge2e v4: 2 speakers per block (grid NS/2). B loaded once per t, feeds both
// speakers' MFMAs -> B L2 traffic halves; SGPR bases; setprio on MFMA clusters.
__global__ __launch_bounds__(512, 3) void ge2e_full(const _Float16* __restrict__ apk,
                                                    const _Float16* __restrict__ bpk,
                                                    const float* __restrict__ cn2,
                                                    const float* __restrict__ dn2,
                                                    const float* __restrict__ wp,
                                                    const float* __restrict__ bp,
                                                    float* __restrict__ out) {
    const int s0 = blockIdx.x * 2, tid = threadIdx.x;
    const int l = tid & 63;
    const int wv = __builtin_amdgcn_readfirstlane(tid >> 6);
    const int l15 = l & 15, lg = l >> 4;

    f4 acc[2][2][4];   // [sp][rt][ct]
    #pragma unroll
    for (int sp = 0; sp < 2; ++sp)
        #pragma unroll
        for (int rt = 0; rt < 2; ++rt)
            #pragma unroll
            for (int ct = 0; ct < 4; ++ct) acc[sp][rt][ct] = (f4){0.f, 0.f, 0.f, 0.f};

    const _Float16* Au = apk + (size_t)s0 * 32 * 1024;         // sp offset = 32*1024
    const _Float16* Bu = bpk + (size_t)(wv * 4) * 16 * 1024;
    const int voff = l * 8;

    #pragma unroll 2
    for (int t = 0; t < 16; ++t) {
        half8 bh[4], bl[4];
        #pragma unroll
        for (int ct = 0; ct < 4; ++ct) {
            const _Float16* p = Bu + (ct * 16 + t) * 1024 + voff;
            bh[ct] = *(const half8*)p;
            bl[ct] = *(const half8*)(p + 512);
        }
        #pragma unroll
        for (int sp = 0; sp < 2; ++sp) {
            half8 ah[2], al[2];
            #pragma unroll
            for (int rt = 0; rt < 2; ++rt) {
                const _Float16* p = Au + sp * 32 * 1024 + (rt * 16 + t) * 1024 + voff;
                ah[rt] = *(const half8*)p;
                al[rt] = *(const half8*)(p + 512);
            }
            __builtin_amdgcn_s_setprio(1);
            #pragma unroll
            for (int ct = 0; ct < 4; ++ct)
                #pragma unroll
                for (int rt = 0; rt < 2; ++rt) {
                    acc[sp][rt][ct] = __builtin_amdgcn_mfma_f32_16x16x32_f16(ah[rt], bh[ct], acc[sp][rt][ct], 0, 0, 0);
                    acc[sp][rt][ct] = __builtin_amdgcn_mfma_f32_16x16x32_f16(ah[rt], bl[ct], acc[sp][rt][ct], 0, 0, 0);
                    acc[sp][rt][ct] = __builtin_amdgcn_mfma_f32_16x16x32_f16(al[rt], bh[ct], acc[sp][rt][ct], 0, 0, 0);
                    acc[sp][rt][ct] = __builtin_amdgcn_mfma_f32_16x16x32_f16(al[rt], bl[ct], acc[sp][rt][ct], 0, 0, 0);
                }
            __builtin_amdgcn_s_setprio(0);
        }
    }

    __shared__ float sDn2[2][32], sSelf[2][32], sMax[2][8][32], sSum[2][8][32], sRow[2][32];
    if (tid < 64) sDn2[tid >> 5][tid & 31] = dn2[(s0 + (tid >> 5)) * NU + (tid & 31)];
    __syncthreads();

    const float w = wp[0], bb = bp[0];

    #pragma unroll
    for (int sp = 0; sp < 2; ++sp) {
        const int s = s0 + sp;
        const float cn2s = cn2[s];
        float dv[2][4];
        #pragma unroll
        for (int rt = 0; rt < 2; ++rt)
            #pragma unroll
            for (int r = 0; r < 4; ++r) dv[rt][r] = sDn2[sp][rt * 16 + lg * 4 + r];

        const bool owner = (wv == (s >> 6)) && (l15 == (s & 15));
        const int  ctd   = (s >> 4) & 3;

        float dotc[2][4];
        #pragma unroll
        for (int ct = 0; ct < 4; ++ct)
            if (ct == ctd)
                #pragma unroll
                for (int rt = 0; rt < 2; ++rt)
                    #pragma unroll
                    for (int r = 0; r < 4; ++r) dotc[rt][r] = acc[sp][rt][ct][r];

        #pragma unroll
        for (int ct = 0; ct < 4; ++ct) {
            const float cv = cn2[wv * 64 + ct * 16 + l15];
            #pragma unroll
            for (int rt = 0; rt < 2; ++rt)
                #pragma unroll
                for (int r = 0; r < 4; ++r)
                    acc[sp][rt][ct][r] = w * (acc[sp][rt][ct][r] / fmaxf(sqrtf(dv[rt][r] * cv), GEPS)) + bb;
        }
        if (owner) {
            #pragma unroll
            for (int rt = 0; rt < 2; ++rt)
                #pragma unroll
                for (int r = 0; r < 4; ++r) {
                    const float d2  = dv[rt][r];
                    const float num = (float)NU * dotc[rt][r] - d2;
                    const float X   = (float)(NU * NU) * cn2s - 2.0f * NU * dotc[rt][r] + d2;
                    const float den = fmaxf(sqrtf(d2) * sqrtf(X), GEPS * (NU - 1));
                    const float ls  = w * (num / den) + bb;
                    #pragma unroll
                    for (int ct = 0; ct < 4; ++ct)
                        if (ct == ctd) acc[sp][rt][ct][r] = ls;
                    sSelf[sp][rt * 16 + lg * 4 + r] = ls;
                }
        }

        #pragma unroll
        for (int rt = 0; rt < 2; ++rt)
            #pragma unroll
            for (int r = 0; r < 4; ++r) {
                float mx = -INFINITY;
                #pragma unroll
                for (int ct = 0; ct < 4; ++ct) mx = fmaxf(mx, acc[sp][rt][ct][r]);
                mx = fmaxf(mx, __shfl_xor(mx, 1)); mx = fmaxf(mx, __shfl_xor(mx, 2));
                mx = fmaxf(mx, __shfl_xor(mx, 4)); mx = fmaxf(mx, __shfl_xor(mx, 8));
                float se = 0.f;
                #pragma unroll
                for (int ct = 0; ct < 4; ++ct) se += expf(acc[sp][rt][ct][r] - mx);
                se += __shfl_xor(se, 1); se += __shfl_xor(se, 2);
                se += __shfl_xor(se, 4); se += __shfl_xor(se, 8);
                if (l15 == 0) {
                    sMax[sp][wv][rt * 16 + lg * 4 + r] = mx;
                    sSum[sp][wv][rt * 16 + lg * 4 + r] = se;
                }
            }
    }
    __syncthreads();

    if (tid < 64) {
        const int sp = tid >> 5, u2 = tid & 31;
        float M = -INFINITY;
        #pragma unroll
        for (int v = 0; v < 8; ++v) M = fmaxf(M, sMax[sp][v][u2]);
        float S = 0.f;
        #pragma unroll
        for (int v = 0; v < 8; ++v) S += sSum[sp][v][u2] * expf(sMax[sp][v][u2] - M);
        sRow[sp][u2] = logf(S) + M - sSelf[sp][u2];
    }
    __syncthreads();
    if (tid == 0) {
        float tot = 0.f;
        #pragma unroll
        for (int sp = 0; sp < 2; ++sp)
            #pragma unroll
            for (int u2 = 0; u2 < 32; ++u2) tot += sRow[sp][u2];
        atomicAdd(out, tot);
    }
}

extern "C" void kernel_launch(void* const* d_in, const int* in_sizes, int n_in,
                              void* d_out, int out_size, void* d_ws, size_t ws_size,
                              hipStream_t stream) {
    const float* dvecs = (const float*)d_in[0];
    const float* w     = (const float*)d_in[1];
    const float* b     = (const float*)d_in[2];
    float* out = (float*)d_out;

    const size_t bpk_b = (size_t)32 * 16 * 1024 * sizeof(_Float16);     // 1 MiB
    const size_t cn2_b = (size_t)NS * sizeof(float);
    const size_t dn2_b = (size_t)NS * NU * sizeof(float);

    char* p = (char*)d_ws;
    _Float16* bpk = (_Float16*)p;                 p += bpk_b;
    float*    cn2 = (float*)p;                    p += cn2_b;
    float*    dn2 = (float*)p;                    p += dn2_b;
    _Float16* apk = (_Float16*)p;

    hipMemsetAsync(d_out, 0, sizeof(float), stream);
    prep_full<<<NS, 256, 0, stream>>>(dvecs, bpk, cn2, dn2, apk);
    ge2e_full<<<NS / 2, 512, 0, stream>>>(apk, bpk, cn2, dn2, w, b, out);
}